// Round 12
// baseline (377.597 us; speedup 1.0000x reference)
//
#include <hip/hip_runtime.h>
#include <math.h>

// x: [B=8, C=1, D=3, H=1536, W=1536] fp32
// out = (x - maxpool3x3x3(x) + 1e-5 > 0) ? x : 0 (pool broadcast over depth).
// Separable: m = depth-max over planes (LDS), mp = 3x3 spatial max of m.
//
// R11: R9's batched-load/register-x/batched-store body + GRID-STRIDE strip
// sweep (the fill/copy access shape).
// Post-mortems: NT stores (R8) and XCD grouping (R10) falsified; R9's
// load/store decoupling was the only win. Remaining delta vs the 6.5 TB/s
// fill / 6.3 TB/s copy on this same chip: those are grid-stride -> at any
// instant the whole GPU forms ONE contiguous moving front per stream. Our
// static block->strip map made ~768 private 48 KB islands x 6 streams ->
// row-activate per burst. Here: 512 persistent blocks (2/CU, all
// co-resident), iteration j processes strip tau = j*512 + i, so the active
// set is always a CONTIGUOUS 512-strip window sweeping the tensor as ~12
// coherent fronts (2 batches x 3 planes, R+W). Body per strip unchanged.

#define Hh   1536
#define Ww   1536
#define EPSf 1e-5f
#define TH   6                  // output rows per strip
#define NRr  (TH + 2)           // LDS rows (with vertical halo) = 8
#define ROWP 1544               // [0..2] dead, [3]=left pad, [4..1539]=cols, [1540]=right pad
#define NSTRIP (Hh / TH)        // 256 strips per batch
#define NTHR 384                // one f4-column per thread
#define NB   512                // persistent blocks (2/CU), 4 iterations
#define NITER (8 * NSTRIP / NB) // 2048 strips / 512 = 4

typedef float f4 __attribute__((ext_vector_type(4)));

__global__ __launch_bounds__(NTHR, 3) void nms3d_kernel(const float* __restrict__ x,
                                                        float* __restrict__ out) {
    __shared__ float sm[NRr][ROWP];     // depth-max rows h0-1 .. h0+TH, 49.4 KB

    const int t = threadIdx.x;
    const size_t plane = (size_t)Hh * Ww;
    const float NI = -INFINITY, PIF = INFINITY;

    for (int j = 0; j < NITER; ++j) {
        const int tau = j * NB + (int)blockIdx.x;   // contiguous window across blocks
        const int s = tau & 255;                    // strip within batch
        const int b = tau >> 8;                     // batch
        const int h0 = s * TH;
        const float* xb = x + (size_t)b * 3 * plane;
        float*       ob = out + (size_t)b * 3 * plane;

        // image-edge pads (cols -1 and W) = -inf
        if (t < 2 * NRr) {
            const int r = t >> 1;
            sm[r][(t & 1) ? 1540 : 3] = NI;
        }

        // ------------- Phase 1: 24 loads up front, depth-max -> LDS --------
        f4 xv[NRr][3];
#pragma unroll
        for (int r = 0; r < NRr; ++r) {
            const int h  = h0 - 1 + r;
            const int hc = h < 0 ? 0 : (h > Hh - 1 ? Hh - 1 : h);
            const float* p = xb + (size_t)hc * Ww + 4 * t;
            xv[r][0] = *(const f4*)(p);
            xv[r][1] = *(const f4*)(p + plane);
            xv[r][2] = *(const f4*)(p + 2 * plane);
        }
        // Fence: keep all 24 loads issued before consumers (consumers are
        // data-dependent LDS stores -> cannot be hoisted above the loads).
        __builtin_amdgcn_sched_barrier(0);

#pragma unroll
        for (int r = 0; r < NRr; ++r) {
            const int h = h0 - 1 + r;
            const float bound = ((unsigned)h < (unsigned)Hh) ? PIF : NI;
            f4 m;
            m.x = fminf(fmaxf(xv[r][0].x, fmaxf(xv[r][1].x, xv[r][2].x)), bound);
            m.y = fminf(fmaxf(xv[r][0].y, fmaxf(xv[r][1].y, xv[r][2].y)), bound);
            m.z = fminf(fmaxf(xv[r][0].z, fmaxf(xv[r][1].z, xv[r][2].z)), bound);
            m.w = fminf(fmaxf(xv[r][0].w, fmaxf(xv[r][1].w, xv[r][2].w)), bound);
            *(f4*)&sm[r][4 + 4 * t] = m;    // conflict-free: lane stride 16B
        }
        __syncthreads();

        // ------------- Phase 2: mp from LDS, mask register-x, batched stores
        f4 mpv[TH];
#pragma unroll
        for (int rr = 0; rr < TH; ++rr) {
            float l = NI, w0v = NI, w1v = NI, w2v = NI, w3v = NI, rt = NI;
#pragma unroll
            for (int dr = 0; dr < 3; ++dr) {
                const float* row = &sm[rr + dr][0];
                const f4 q0 = *(const f4*)&row[4 * t];       // .w = col 4t-1
                const f4 q1 = *(const f4*)&row[4 * t + 4];   // cols 4t..4t+3
                const f4 q2 = *(const f4*)&row[4 * t + 8];   // .x = col 4t+4
                l   = fmaxf(l,   q0.w);
                w0v = fmaxf(w0v, q1.x);
                w1v = fmaxf(w1v, q1.y);
                w2v = fmaxf(w2v, q1.z);
                w3v = fmaxf(w3v, q1.w);
                rt  = fmaxf(rt,  q2.x);
            }
            mpv[rr].x = fmaxf(l,   fmaxf(w0v, w1v));
            mpv[rr].y = fmaxf(w0v, fmaxf(w1v, w2v));
            mpv[rr].z = fmaxf(w1v, fmaxf(w2v, w3v));
            mpv[rr].w = fmaxf(w2v, fmaxf(w3v, rt));
        }

        // All 18 stores, plane-major: 6 consecutive full rows per plane.
#pragma unroll
        for (int d = 0; d < 3; ++d) {
            float* pd = ob + (size_t)d * plane + (size_t)h0 * Ww + 4 * t;
#pragma unroll
            for (int rr = 0; rr < TH; ++rr) {
                const f4 a = xv[rr + 1][d];      // x held in registers since phase 1
                const f4 mp = mpv[rr];
                f4 o;
                o.x = ((a.x - mp.x) + EPSf > 0.0f) ? a.x : 0.0f;
                o.y = ((a.y - mp.y) + EPSf > 0.0f) ? a.y : 0.0f;
                o.z = ((a.z - mp.z) + EPSf > 0.0f) ? a.z : 0.0f;
                o.w = ((a.w - mp.w) + EPSf > 0.0f) ? a.w : 0.0f;
                *(f4*)(pd + (size_t)rr * Ww) = o;
            }
        }

        // protect LDS reuse across iterations (phase-1 writes of j+1 vs
        // phase-2 reads of j by slower waves)
        __syncthreads();
    }
}

extern "C" void kernel_launch(void* const* d_in, const int* in_sizes, int n_in,
                              void* d_out, int out_size, void* d_ws, size_t ws_size,
                              hipStream_t stream) {
    const float* x = (const float*)d_in[0];
    float* out = (float*)d_out;
    nms3d_kernel<<<dim3(NB), dim3(NTHR), 0, stream>>>(x, out);
}

// Round 13
// 373.174 us; speedup vs baseline: 1.0119x; 1.0119x over previous
//
#include <hip/hip_runtime.h>
#include <math.h>

// x: [B=8, C=1, D=3, H=1536, W=1536] fp32
// out = (x - maxpool3x3x3(x) + 1e-5 > 0) ? x : 0 (pool broadcast over depth).
// Separable: m = depth-max over planes (LDS), mp = 3x3 spatial max of m.
//
// R12: R9's batched-load/register-x/batched-store body at HALF-ROW block
// granularity (768 cols, 192 thr, LDS 24.25 KB).
// Post-mortems: NT stores (R8), XCD grouping (R10), grid-stride sweep (R11)
// all neutral -> DRAM-side access-shape theories dead. Surviving theory:
// with 49.4 KB LDS only 3 barrier-locked blocks fit per CU; during each
// block's LDS-compute+store phase it issues ZERO reads, and 3 coarse phase
// domains leave the CU's read stream duty-cycled -> ~45% HBM efficiency.
// Halving block width doubles independent barrier domains per CU (5-6),
// interleaving phases finely so reads stay continuously issued. Same TH,
// same load/store discipline; +1 seam halo column (+0.3% reads).

#define Hh   1536
#define Ww   1536
#define EPSf 1e-5f
#define TH   6                  // output rows per block
#define NRr  (TH + 2)           // rows incl. vertical halo = 8
#define HW   768                // cols per block (half row)
#define ROWP 776                // [0..2] dead, [3]=left pad, [4..771]=cols, [772]=right pad
#define NSTRIP (Hh / TH)        // 256 strips per batch
#define NTHR 192                // one f4-column per thread (192*4 = 768)

typedef float f4 __attribute__((ext_vector_type(4)));

__global__ __launch_bounds__(NTHR, 4) void nms3d_kernel(const float* __restrict__ x,
                                                        float* __restrict__ out) {
    __shared__ float sm[NRr][ROWP];     // depth-max rows h0-1 .. h0+TH, 24.25 KB

    const int t   = threadIdx.x;
    const int bid = blockIdx.x;
    const int half = bid & 1;           // which half-row
    const int s    = (bid >> 1) & 255;  // strip (adjacent bids = same/adjacent strips)
    const int b    = bid >> 9;          // batch

    const int h0 = s * TH;
    const int c0 = half * HW;           // base column of this block
    const size_t plane = (size_t)Hh * Ww;
    const float* xb = x + (size_t)b * 3 * plane;
    float*       ob = out + (size_t)b * 3 * plane;

    const float NI = -INFINITY, PIF = INFINITY;

    // ---------------- Phase 1: all loads up front ---------------------------
    // Main: 8 rows x 3 planes, 192 thr x 16 B contiguous = 3 KB/row/plane.
    f4 xv[NRr][3];
#pragma unroll
    for (int r = 0; r < NRr; ++r) {
        const int h  = h0 - 1 + r;
        const int hc = h < 0 ? 0 : (h > Hh - 1 ? Hh - 1 : h);
        const float* p = xb + (size_t)hc * Ww + c0 + 4 * t;
        xv[r][0] = *(const f4*)(p);
        xv[r][1] = *(const f4*)(p + plane);
        xv[r][2] = *(const f4*)(p + 2 * plane);
    }
    // Seam-pad loads: threads t<16 fetch the single column just outside each
    // edge (3 planes x 1 scalar each; L2/L3-hot -- neighbor block's lines).
    float pv0 = 0.f, pv1 = 0.f, pv2 = 0.f;
    bool pvalid = false;
    if (t < 2 * NRr) {
        const int r    = t >> 1;
        const int side = t & 1;                     // 0=left pad, 1=right pad
        const int col  = side ? (c0 + HW) : (c0 - 1);
        pvalid = (col >= 0) && (col < Ww);
        if (pvalid) {
            const int h  = h0 - 1 + r;
            const int hc = h < 0 ? 0 : (h > Hh - 1 ? Hh - 1 : h);
            const float* q = xb + (size_t)hc * Ww + col;
            pv0 = q[0]; pv1 = q[plane]; pv2 = q[2 * plane];
        }
    }
    // Fence: keep all loads issued before consumers (consumers are
    // data-dependent LDS stores -> cannot be hoisted above the loads).
    __builtin_amdgcn_sched_barrier(0);

    // depth-max -> LDS
#pragma unroll
    for (int r = 0; r < NRr; ++r) {
        const int h = h0 - 1 + r;
        const float bound = ((unsigned)h < (unsigned)Hh) ? PIF : NI;
        f4 m;
        m.x = fminf(fmaxf(xv[r][0].x, fmaxf(xv[r][1].x, xv[r][2].x)), bound);
        m.y = fminf(fmaxf(xv[r][0].y, fmaxf(xv[r][1].y, xv[r][2].y)), bound);
        m.z = fminf(fmaxf(xv[r][0].z, fmaxf(xv[r][1].z, xv[r][2].z)), bound);
        m.w = fminf(fmaxf(xv[r][0].w, fmaxf(xv[r][1].w, xv[r][2].w)), bound);
        *(f4*)&sm[r][4 + 4 * t] = m;    // conflict-free: lane stride 16B
    }
    if (t < 2 * NRr) {
        const int r    = t >> 1;
        const int side = t & 1;
        float pm = NI;
        if (pvalid) {
            const int h = h0 - 1 + r;
            const float bound = ((unsigned)h < (unsigned)Hh) ? PIF : NI;
            pm = fminf(fmaxf(pv0, fmaxf(pv1, pv2)), bound);
        }
        sm[r][side ? 772 : 3] = pm;
    }
    __syncthreads();

    // ---------------- Phase 2: mp from LDS, mask register-x, store ----------
    // Stores folded per output row (frees mp registers; all loads already
    // retired, so stores never sit in front of a load wait).
#pragma unroll
    for (int rr = 0; rr < TH; ++rr) {
        float l = NI, w0v = NI, w1v = NI, w2v = NI, w3v = NI, rt = NI;
#pragma unroll
        for (int dr = 0; dr < 3; ++dr) {
            const float* row = &sm[rr + dr][0];
            const f4 q0 = *(const f4*)&row[4 * t];       // .w = col 4t-1
            const f4 q1 = *(const f4*)&row[4 * t + 4];   // cols 4t..4t+3
            const f4 q2 = *(const f4*)&row[4 * t + 8];   // .x = col 4t+4
            l   = fmaxf(l,   q0.w);
            w0v = fmaxf(w0v, q1.x);
            w1v = fmaxf(w1v, q1.y);
            w2v = fmaxf(w2v, q1.z);
            w3v = fmaxf(w3v, q1.w);
            rt  = fmaxf(rt,  q2.x);
        }
        f4 mp;
        mp.x = fmaxf(l,   fmaxf(w0v, w1v));
        mp.y = fmaxf(w0v, fmaxf(w1v, w2v));
        mp.z = fmaxf(w1v, fmaxf(w2v, w3v));
        mp.w = fmaxf(w2v, fmaxf(w3v, rt));

        float* po = ob + (size_t)(h0 + rr) * Ww + c0 + 4 * t;
#pragma unroll
        for (int d = 0; d < 3; ++d) {
            const f4 a = xv[rr + 1][d];      // x held in registers since phase 1
            f4 o;
            o.x = ((a.x - mp.x) + EPSf > 0.0f) ? a.x : 0.0f;
            o.y = ((a.y - mp.y) + EPSf > 0.0f) ? a.y : 0.0f;
            o.z = ((a.z - mp.z) + EPSf > 0.0f) ? a.z : 0.0f;
            o.w = ((a.w - mp.w) + EPSf > 0.0f) ? a.w : 0.0f;
            *(f4*)(po + (size_t)d * plane) = o;
        }
    }
}

extern "C" void kernel_launch(void* const* d_in, const int* in_sizes, int n_in,
                              void* d_out, int out_size, void* d_ws, size_t ws_size,
                              hipStream_t stream) {
    const float* x = (const float*)d_in[0];
    float* out = (float*)d_out;
    const int grid = 8 * NSTRIP * 2;   // 4096 blocks (batch-major, strip, half)
    nms3d_kernel<<<dim3(grid), dim3(NTHR), 0, stream>>>(x, out);
}